// Round 8
// baseline (99.721 us; speedup 1.0000x reference)
//
#include <hip/hip_runtime.h>
#include <math.h>

#define KN 1024
#define KB 128
#define KDT 0.1f
#define KSTEPS 10
#define KMAGIC 0x5A170000u
#define KPOISON 0xAAAAAAAAu    // documented d_ws poison value (0xAA bytes)
#define PI_F 3.14159265358979f
#define TWO_PI_F 6.28318530717959f

typedef __attribute__((ext_vector_type(8))) short short8;
typedef __attribute__((ext_vector_type(4))) float floatx4;
typedef unsigned long long u64;

__device__ __forceinline__ unsigned short f2bf(float f) {
    unsigned u = __float_as_uint(f);
    u += 0x7FFF + ((u >> 16) & 1);          // round-to-nearest-even
    return (unsigned short)(u >> 16);
}

// X layout (fragment order, per group g = b>>4; 16384 dwords per group).
// Element (b15 = b&15, k): chunk=k>>5, quad=(k>>3)&3, jj=(k>>1)&3, p=k&1
//   dword idx = g*16384 + chunk*512 + jj*128 + quad*32 + b15*2 + p
// Consumer wave kq, lane L (r16=L&15, quad=L>>4), it, jj reads u64 at
//   g*8192 + (kq*4+it)*256 + jj*64 + L   -> dense 512 B per wave instruction.
__device__ __forceinline__ unsigned xidx(int grp, int b15, int k) {
    return (unsigned)(grp * 16384 + (k >> 5) * 512 + ((k >> 1) & 3) * 128 +
                      ((k >> 3) & 3) * 32 + b15 * 2 + (k & 1));
}

// Single kernel, plain launch (graph-capturable).
// Grid 256 = 8 batch-groups(16 b) x 32 i-blocks(32 cols); block 512 thr = 8 waves.
// Wave = kq (k-eighth). K in registers (read once). X exchanged via relaxed
// agent atomics (L3-coherent, fence-free — R5 lesson). Barrier v2: per-group
// arrival counter + single go-flag; one scalar poller per block (R7 lesson:
// 32-lane slot gathers from 256 blocks congest the slot lines).
__global__ __launch_bounds__(512)
void k_main(const float* __restrict__ theta0,
            const float* __restrict__ Kmat,
            const float* __restrict__ omega,
            const float* __restrict__ kg,
            float* __restrict__ out_theta,
            float* __restrict__ out_coh,
            unsigned* __restrict__ slots,        // [0..255]: ctr @ g*32; go @ 256+g*32
            float* __restrict__ acc,             // coherence accum: 2*128 slots, 64B stride
            unsigned* __restrict__ xA,
            unsigned* __restrict__ xB)
{
    const int grp = blockIdx.x >> 5;
    const int b0  = grp * 16;
    const int i0  = (blockIdx.x & 31) * 32;

    const int tid  = threadIdx.x;
    const int lane = tid & 63;
    const int kq   = tid >> 6;              // wave = k-eighth
    const int r16  = lane & 15;
    const int quad = lane >> 4;

    __shared__ float ldsY[8][2][16][34];    // [kq][S/C][m][il+pad] 34.8 KB

    unsigned* cnt = &slots[grp * 32];            // one 128 B line per group
    unsigned* go  = &slots[256 + grp * 32];      // separate line per group

    // group leader zeroes its coherence accumulators (64 B stride slots)
    if ((blockIdx.x & 31) == 0 && tid < 16) {
        __hip_atomic_store(&acc[(b0 + tid) * 16], 0.f, __ATOMIC_RELAXED,
                           __HIP_MEMORY_SCOPE_AGENT);
        __hip_atomic_store(&acc[2048 + (b0 + tid) * 16], 0.f, __ATOMIC_RELAXED,
                           __HIP_MEMORY_SCOPE_AGENT);
    }

    // ---- B fragments (both wi) fp32->bf16 into registers; K symmetric.
    short8 bfrag[2][4];
    #pragma unroll
    for (int wi = 0; wi < 2; ++wi) {
        const float* kp = Kmat + (size_t)(i0 + wi * 16 + r16) * KN + kq * 128 + quad * 8;
        #pragma unroll
        for (int it = 0; it < 4; ++it) {
            const float4 v0 = *reinterpret_cast<const float4*>(kp + it * 32);
            const float4 v1 = *reinterpret_cast<const float4*>(kp + it * 32 + 4);
            short8 b_;
            b_[0] = (short)f2bf(v0.x); b_[1] = (short)f2bf(v0.y);
            b_[2] = (short)f2bf(v0.z); b_[3] = (short)f2bf(v0.w);
            b_[4] = (short)f2bf(v1.x); b_[5] = (short)f2bf(v1.y);
            b_[6] = (short)f2bf(v1.z); b_[7] = (short)f2bf(v1.w);
            bfrag[wi][it] = b_;
        }
    }

    // ---- per-thread theta state (block-private tile, 1 elem/thread).
    // Carry (sn,cs) = sincos(theta) across steps (2pi-periodic => wrap-invariant).
    const int eb = b0 + (tid >> 5);          // batch
    const int ei = i0 + (tid & 31);          // column
    float th_reg = theta0[(size_t)eb * KN + ei];
    const float omg = omega[ei];
    float sn, cs;
    __sincosf(th_reg, &sn, &cs);
    __hip_atomic_store(&xA[xidx(grp, eb & 15, ei)],
                       (unsigned)f2bf(sn) | ((unsigned)f2bf(cs) << 16),
                       __ATOMIC_RELAXED, __HIP_MEMORY_SCOPE_AGENT);
    const float scale = kg[0] * (1.0f / (float)KN);

    unsigned nbar = 0;
    auto arrive_wait = [&]() {
        ++nbar;
        __syncthreads();                     // drains vmcnt: this block's X at L3
        if (tid == 0) {
            // arrival: counter starts at KPOISON (harness 0xAA poison, documented)
            unsigned old = __hip_atomic_fetch_add(cnt, 1u, __ATOMIC_RELAXED,
                                                  __HIP_MEMORY_SCOPE_AGENT);
            if (old == KPOISON + 32u * nbar - 1u) {
                // last arriver: all 32 blocks' X stores are L3-resident -> go
                __hip_atomic_store(go, KMAGIC + nbar, __ATOMIC_RELAXED,
                                   __HIP_MEMORY_SCOPE_AGENT);
            } else {
                unsigned polls = 0;
                while (__hip_atomic_load(go, __ATOMIC_RELAXED,
                                         __HIP_MEMORY_SCOPE_AGENT) != KMAGIC + nbar) {
                    __builtin_amdgcn_s_sleep(2);
                    if (++polls > 4000000u) break;   // failsafe: fail visibly
                }
            }
        }
        __syncthreads();
    };

    arrive_wait();                           // phase 1: X init visible

    const unsigned* xcur = xA;
    unsigned* xnxt = xB;
    float s2 = sn, c2 = cs;
    for (int s = 0; s < KSTEPS; ++s) {
        // ---- A stage: 16 dense coherent u64 loads (512 B/wave-instr)
        const u64* xg = (const u64*)xcur + grp * 8192 + kq * 1024 + lane;
        u64 aw[4][4];
        #pragma unroll
        for (int it = 0; it < 4; ++it)
            #pragma unroll
            for (int jj = 0; jj < 4; ++jj)
                aw[it][jj] = __hip_atomic_load((u64*)(xg + it * 256 + jj * 64),
                                               __ATOMIC_RELAXED,
                                               __HIP_MEMORY_SCOPE_AGENT);
        // ---- extract + MFMA (both wi subtiles)
        floatx4 accS[2] = {{0.f,0.f,0.f,0.f},{0.f,0.f,0.f,0.f}};
        floatx4 accC[2] = {{0.f,0.f,0.f,0.f},{0.f,0.f,0.f,0.f}};
        #pragma unroll
        for (int it = 0; it < 4; ++it) {
            short8 a_s, a_c;
            #pragma unroll
            for (int jj = 0; jj < 4; ++jj) {
                unsigned lo = (unsigned)aw[it][jj];
                unsigned hi = (unsigned)(aw[it][jj] >> 32);
                a_s[jj * 2]     = (short)(lo & 0xffffu);
                a_c[jj * 2]     = (short)(lo >> 16);
                a_s[jj * 2 + 1] = (short)(hi & 0xffffu);
                a_c[jj * 2 + 1] = (short)(hi >> 16);
            }
            #pragma unroll
            for (int wi = 0; wi < 2; ++wi) {
                accS[wi] = __builtin_amdgcn_mfma_f32_16x16x32_bf16(a_s, bfrag[wi][it], accS[wi], 0, 0, 0);
                accC[wi] = __builtin_amdgcn_mfma_f32_16x16x32_bf16(a_c, bfrag[wi][it], accC[wi], 0, 0, 0);
            }
        }
        #pragma unroll
        for (int wi = 0; wi < 2; ++wi)
            #pragma unroll
            for (int r = 0; r < 4; ++r) {
                ldsY[kq][0][quad * 4 + r][wi * 16 + r16] = accS[wi][r];  // D[m=quad*4+r][n=r16]
                ldsY[kq][1][quad * 4 + r][wi * 16 + r16] = accC[wi][r];
            }
        __syncthreads();

        // ---- Euler update + branch-wrap (1 elem/thread)
        {
            const int bl = tid >> 5, ilo = tid & 31;
            float Ys = 0.f, Yc = 0.f;
            #pragma unroll
            for (int q = 0; q < 8; ++q) {
                Ys += ldsY[q][0][bl][ilo];
                Yc += ldsY[q][1][bl][ilo];
            }
            const float coupling = cs * Ys - sn * Yc;   // sum_j K[i,j] sin(th_j - th_i)
            float tn = th_reg + KDT * (omg + scale * coupling);
            __sincosf(tn, &s2, &c2);                    // also next step's (sn,cs)
            // wrap to (-pi, pi] — equals atan2f(s2,c2) to ~1e-7 (|tn| < 3*pi)
            if (tn > PI_F)       tn -= TWO_PI_F;
            else if (tn < -PI_F) tn += TWO_PI_F;
            th_reg = tn;
            sn = s2; cs = c2;
        }
        if (s < KSTEPS - 1) {
            __hip_atomic_store(&xnxt[xidx(grp, eb & 15, ei)],
                               (unsigned)f2bf(s2) | ((unsigned)f2bf(c2) << 16),
                               __ATOMIC_RELAXED, __HIP_MEMORY_SCOPE_AGENT);
            arrive_wait();                   // phases 2..10
            const unsigned* t = xcur; xcur = xnxt; xnxt = (unsigned*)t;
        } else {
            out_theta[(size_t)eb * KN + ei] = th_reg;
        }
    }

    // ---- coherence: block-local reduce over its 32 cols, then padded atomics
    __syncthreads();
    float* red = &ldsY[0][0][0][0];
    red[tid]       = s2;                     // == sin(theta_final) to ~1e-7
    red[512 + tid] = c2;
    __syncthreads();
    if (tid < 16) {
        float ss = 0.f, cc = 0.f;
        #pragma unroll
        for (int il2 = 0; il2 < 32; ++il2) {
            ss += red[tid * 32 + il2];
            cc += red[512 + tid * 32 + il2];
        }
        atomicAdd(&acc[(b0 + tid) * 16], ss);           // 64B-stride slots
        atomicAdd(&acc[2048 + (b0 + tid) * 16], cc);
    }
    arrive_wait();                           // final phase: group's adds visible
    if ((blockIdx.x & 31) == 0 && tid < 16) {
        float sv = __hip_atomic_load(&acc[(b0 + tid) * 16],
                                     __ATOMIC_RELAXED, __HIP_MEMORY_SCOPE_AGENT);
        float cv = __hip_atomic_load(&acc[2048 + (b0 + tid) * 16],
                                     __ATOMIC_RELAXED, __HIP_MEMORY_SCOPE_AGENT);
        float sm = sv * (1.0f / (float)KN);
        float cm = cv * (1.0f / (float)KN);
        out_coh[b0 + tid] = sqrtf(cm * cm + sm * sm);
    }
}

extern "C" void kernel_launch(void* const* d_in, const int* in_sizes, int n_in,
                              void* d_out, int out_size, void* d_ws, size_t ws_size,
                              hipStream_t stream)
{
    (void)in_sizes; (void)n_in; (void)out_size; (void)ws_size;

    const float* theta0 = (const float*)d_in[0];
    const float* Kmat   = (const float*)d_in[1];
    const float* omega  = (const float*)d_in[2];
    const float* kg     = (const float*)d_in[3];

    float* out_theta = (float*)d_out;                    // 128*1024 f32
    float* out_coh   = out_theta + (size_t)KB * KN;      // +128 f32

    // ws: slots[512] u32 @0 (2 KB) | acc 16 KB @4096 | xA 512 KB | xB 512 KB
    unsigned* slots = (unsigned*)d_ws;
    float* acc      = (float*)((char*)d_ws + 4096);
    unsigned* xA    = (unsigned*)((char*)d_ws + 4096 + 16384);
    unsigned* xB    = xA + (size_t)KB * KN;

    k_main<<<256, 512, 0, stream>>>(theta0, Kmat, omega, kg,
                                    out_theta, out_coh, slots, acc, xA, xB);
}

// Round 9
// 97.892 us; speedup vs baseline: 1.0187x; 1.0187x over previous
//
#include <hip/hip_runtime.h>
#include <math.h>

#define KN 1024
#define KB 128
#define KDT 0.1f
#define KSTEPS 10
#define KMAGIC 0xB0000000u     // > 0xAAAAAAAA poison: stale poison never passes >=
#define PI_F 3.14159265358979f
#define TWO_PI_F 6.28318530717959f

typedef __attribute__((ext_vector_type(8))) short short8;
typedef __attribute__((ext_vector_type(4))) float floatx4;
typedef unsigned long long u64;

__device__ __forceinline__ unsigned short f2bf(float f) {
    unsigned u = __float_as_uint(f);
    u += 0x7FFF + ((u >> 16) & 1);          // round-to-nearest-even
    return (unsigned short)(u >> 16);
}

// X layout (fragment order, per group g = b>>4; 16384 dwords per group).
// Element (b15 = b&15, k): chunk=k>>5, quad=(k>>3)&3, jj=(k>>1)&3, p=k&1
//   dword idx = g*16384 + chunk*512 + jj*128 + quad*32 + b15*2 + p
// Chunk c is written entirely by producer block (g, ib=c) (its 32 cols).
// Consumer wave kq reads chunks kq*4..kq*4+3 -> depends on exactly 4 producers.
__device__ __forceinline__ unsigned xidx(int grp, int b15, int k) {
    return (unsigned)(grp * 16384 + (k >> 5) * 512 + ((k >> 1) & 3) * 128 +
                      ((k >> 3) & 3) * 32 + b15 * 2 + (k & 1));
}

// Single kernel, plain launch (graph-capturable).
// Grid 256 = 8 batch-groups(16 b) x 32 i-blocks(32 cols); block 512 thr = 8 waves.
// DATAFLOW exchange (R8 lesson: group barrier = 4 serial L3 RTs + max-over-32
// skew): per-producer monotone ready-flags; each wave polls only its 4
// producers (one 128 B line) and proceeds. X via relaxed agent atomics
// (L3-coherent, fence-free — R5 lesson). K in registers (read once).
__global__ __launch_bounds__(512)
void k_main(const float* __restrict__ theta0,
            const float* __restrict__ Kmat,
            const float* __restrict__ omega,
            const float* __restrict__ kg,
            float* __restrict__ out_theta,
            float* __restrict__ out_coh,
            unsigned* __restrict__ flags,        // 256 contiguous; group g = [g*32, g*32+32)
            float* __restrict__ acc,             // coherence accum: 2*128 slots, 64B stride
            unsigned* __restrict__ xA,
            unsigned* __restrict__ xB)
{
    const int grp = blockIdx.x >> 5;
    const int b0  = grp * 16;
    const int i0  = (blockIdx.x & 31) * 32;

    const int tid  = threadIdx.x;
    const int lane = tid & 63;
    const int kq   = tid >> 6;              // wave = k-eighth
    const int r16  = lane & 15;
    const int quad = lane >> 4;

    __shared__ float ldsY[8][2][16][34];    // [kq][S/C][m][il+pad] 34.8 KB

    // group leader zeroes its coherence accumulators (before publishing flag 0,
    // so every block's end-of-kernel atomicAdd is ordered after the zeroing)
    if ((blockIdx.x & 31) == 0 && tid < 16) {
        __hip_atomic_store(&acc[(b0 + tid) * 16], 0.f, __ATOMIC_RELAXED,
                           __HIP_MEMORY_SCOPE_AGENT);
        __hip_atomic_store(&acc[2048 + (b0 + tid) * 16], 0.f, __ATOMIC_RELAXED,
                           __HIP_MEMORY_SCOPE_AGENT);
    }

    // ---- B fragments (both wi) fp32->bf16 into registers; K symmetric.
    short8 bfrag[2][4];
    #pragma unroll
    for (int wi = 0; wi < 2; ++wi) {
        const float* kp = Kmat + (size_t)(i0 + wi * 16 + r16) * KN + kq * 128 + quad * 8;
        #pragma unroll
        for (int it = 0; it < 4; ++it) {
            const float4 v0 = *reinterpret_cast<const float4*>(kp + it * 32);
            const float4 v1 = *reinterpret_cast<const float4*>(kp + it * 32 + 4);
            short8 b_;
            b_[0] = (short)f2bf(v0.x); b_[1] = (short)f2bf(v0.y);
            b_[2] = (short)f2bf(v0.z); b_[3] = (short)f2bf(v0.w);
            b_[4] = (short)f2bf(v1.x); b_[5] = (short)f2bf(v1.y);
            b_[6] = (short)f2bf(v1.z); b_[7] = (short)f2bf(v1.w);
            bfrag[wi][it] = b_;
        }
    }

    // ---- per-thread theta state (block-private tile, 1 elem/thread).
    const int eb = b0 + (tid >> 5);          // batch
    const int ei = i0 + (tid & 31);          // column
    float th_reg = theta0[(size_t)eb * KN + ei];
    const float omg = omega[ei];
    float sn, cs;
    __sincosf(th_reg, &sn, &cs);
    __hip_atomic_store(&xA[xidx(grp, eb & 15, ei)],
                       (unsigned)f2bf(sn) | ((unsigned)f2bf(cs) << 16),
                       __ATOMIC_RELAXED, __HIP_MEMORY_SCOPE_AGENT);
    const float scale = kg[0] * (1.0f / (float)KN);

    __syncthreads();                         // drain X(0) stores (vmcnt(0))
    if (tid == 0)
        __hip_atomic_store(&flags[blockIdx.x], KMAGIC + 0u,
                           __ATOMIC_RELAXED, __HIP_MEMORY_SCOPE_AGENT);

    // Per-wave dataflow wait: lanes 0..3 poll this wave's 4 producer flags
    // (contiguous -> single 128 B line). Monotone >= compare.
    auto wait_chunks = [&](unsigned tgt) {
        unsigned polls = 0;
        for (;;) {
            unsigned v = tgt;
            if (lane < 4)
                v = __hip_atomic_load(&flags[grp * 32 + kq * 4 + lane],
                                      __ATOMIC_RELAXED, __HIP_MEMORY_SCOPE_AGENT);
            if (__ballot(v >= tgt) == ~0ull) break;
            if (++polls > 4000000u) break;   // failsafe: fail visibly, not hang
            __builtin_amdgcn_s_sleep(2);
        }
    };

    const unsigned* xcur = xA;
    unsigned* xnxt = xB;
    float s2 = sn, c2 = cs;
    for (int s = 0; s < KSTEPS; ++s) {
        wait_chunks(KMAGIC + (unsigned)s);   // X(s) chunks for this wave ready

        // ---- A stage: 16 dense coherent u64 loads (512 B/wave-instr)
        const u64* xg = (const u64*)xcur + grp * 8192 + kq * 1024 + lane;
        u64 aw[4][4];
        #pragma unroll
        for (int it = 0; it < 4; ++it)
            #pragma unroll
            for (int jj = 0; jj < 4; ++jj)
                aw[it][jj] = __hip_atomic_load((u64*)(xg + it * 256 + jj * 64),
                                               __ATOMIC_RELAXED,
                                               __HIP_MEMORY_SCOPE_AGENT);
        // ---- extract + MFMA (both wi subtiles)
        floatx4 accS[2] = {{0.f,0.f,0.f,0.f},{0.f,0.f,0.f,0.f}};
        floatx4 accC[2] = {{0.f,0.f,0.f,0.f},{0.f,0.f,0.f,0.f}};
        #pragma unroll
        for (int it = 0; it < 4; ++it) {
            short8 a_s, a_c;
            #pragma unroll
            for (int jj = 0; jj < 4; ++jj) {
                unsigned lo = (unsigned)aw[it][jj];
                unsigned hi = (unsigned)(aw[it][jj] >> 32);
                a_s[jj * 2]     = (short)(lo & 0xffffu);
                a_c[jj * 2]     = (short)(lo >> 16);
                a_s[jj * 2 + 1] = (short)(hi & 0xffffu);
                a_c[jj * 2 + 1] = (short)(hi >> 16);
            }
            #pragma unroll
            for (int wi = 0; wi < 2; ++wi) {
                accS[wi] = __builtin_amdgcn_mfma_f32_16x16x32_bf16(a_s, bfrag[wi][it], accS[wi], 0, 0, 0);
                accC[wi] = __builtin_amdgcn_mfma_f32_16x16x32_bf16(a_c, bfrag[wi][it], accC[wi], 0, 0, 0);
            }
        }
        #pragma unroll
        for (int wi = 0; wi < 2; ++wi)
            #pragma unroll
            for (int r = 0; r < 4; ++r) {
                ldsY[kq][0][quad * 4 + r][wi * 16 + r16] = accS[wi][r];  // D[m=quad*4+r][n=r16]
                ldsY[kq][1][quad * 4 + r][wi * 16 + r16] = accC[wi][r];
            }
        __syncthreads();

        // ---- Euler update + branch-wrap (1 elem/thread)
        {
            const int bl = tid >> 5, ilo = tid & 31;
            float Ys = 0.f, Yc = 0.f;
            #pragma unroll
            for (int q = 0; q < 8; ++q) {
                Ys += ldsY[q][0][bl][ilo];
                Yc += ldsY[q][1][bl][ilo];
            }
            const float coupling = cs * Ys - sn * Yc;   // sum_j K[i,j] sin(th_j - th_i)
            float tn = th_reg + KDT * (omg + scale * coupling);
            __sincosf(tn, &s2, &c2);                    // also next step's (sn,cs)
            if (tn > PI_F)       tn -= TWO_PI_F;        // == atan2f(s2,c2) to ~1e-7
            else if (tn < -PI_F) tn += TWO_PI_F;
            th_reg = tn;
            sn = s2; cs = c2;
        }
        if (s < KSTEPS - 1) {
            __hip_atomic_store(&xnxt[xidx(grp, eb & 15, ei)],
                               (unsigned)f2bf(s2) | ((unsigned)f2bf(c2) << 16),
                               __ATOMIC_RELAXED, __HIP_MEMORY_SCOPE_AGENT);
            __syncthreads();                 // drain X(s+1) stores; guards ldsY reuse
            if (tid == 0)
                __hip_atomic_store(&flags[blockIdx.x], KMAGIC + (unsigned)(s + 1),
                                   __ATOMIC_RELAXED, __HIP_MEMORY_SCOPE_AGENT);
            const unsigned* t = xcur; xcur = xnxt; xnxt = (unsigned*)t;
        } else {
            out_theta[(size_t)eb * KN + ei] = th_reg;
        }
    }

    // ---- coherence: block-local reduce over its 32 cols, then padded atomics
    __syncthreads();                         // epilogue ldsY reads done
    float* red = &ldsY[0][0][0][0];
    red[tid]       = s2;                     // == sin(theta_final) to ~1e-7
    red[512 + tid] = c2;
    __syncthreads();
    if (tid < 16) {
        float ss = 0.f, cc = 0.f;
        #pragma unroll
        for (int il2 = 0; il2 < 32; ++il2) {
            ss += red[tid * 32 + il2];
            cc += red[512 + tid * 32 + il2];
        }
        atomicAdd(&acc[(b0 + tid) * 16], ss);           // 64B-stride slots
        atomicAdd(&acc[2048 + (b0 + tid) * 16], cc);
    }
    __syncthreads();                         // drain atomics (vmcnt(0))
    if (tid == 0)
        __hip_atomic_store(&flags[blockIdx.x], KMAGIC + (unsigned)KSTEPS,
                           __ATOMIC_RELAXED, __HIP_MEMORY_SCOPE_AGENT);

    // group leader: wait all 32 blocks' adds, then write out_coh
    if ((blockIdx.x & 31) == 0) {
        if (tid < 64) {
            const unsigned tgt = KMAGIC + (unsigned)KSTEPS;
            unsigned polls = 0;
            for (;;) {
                unsigned v = tgt;
                if (lane < 32)
                    v = __hip_atomic_load(&flags[grp * 32 + lane],
                                          __ATOMIC_RELAXED, __HIP_MEMORY_SCOPE_AGENT);
                if (__ballot(v >= tgt) == ~0ull) break;
                if (++polls > 4000000u) break;
                __builtin_amdgcn_s_sleep(2);
            }
        }
        __syncthreads();
        if (tid < 16) {
            float sv = __hip_atomic_load(&acc[(b0 + tid) * 16],
                                         __ATOMIC_RELAXED, __HIP_MEMORY_SCOPE_AGENT);
            float cv = __hip_atomic_load(&acc[2048 + (b0 + tid) * 16],
                                         __ATOMIC_RELAXED, __HIP_MEMORY_SCOPE_AGENT);
            float sm = sv * (1.0f / (float)KN);
            float cm = cv * (1.0f / (float)KN);
            out_coh[b0 + tid] = sqrtf(cm * cm + sm * sm);
        }
    }
}

extern "C" void kernel_launch(void* const* d_in, const int* in_sizes, int n_in,
                              void* d_out, int out_size, void* d_ws, size_t ws_size,
                              hipStream_t stream)
{
    (void)in_sizes; (void)n_in; (void)out_size; (void)ws_size;

    const float* theta0 = (const float*)d_in[0];
    const float* Kmat   = (const float*)d_in[1];
    const float* omega  = (const float*)d_in[2];
    const float* kg     = (const float*)d_in[3];

    float* out_theta = (float*)d_out;                    // 128*1024 f32
    float* out_coh   = out_theta + (size_t)KB * KN;      // +128 f32

    // ws: flags[256] u32 @0 (1 KB) | acc 16 KB @4096 | xA 512 KB | xB 512 KB
    unsigned* flags = (unsigned*)d_ws;
    float* acc      = (float*)((char*)d_ws + 4096);
    unsigned* xA    = (unsigned*)((char*)d_ws + 4096 + 16384);
    unsigned* xB    = xA + (size_t)KB * KN;

    k_main<<<256, 512, 0, stream>>>(theta0, Kmat, omega, kg,
                                    out_theta, out_coh, flags, acc, xA, xB);
}